// Round 4
// baseline (267.025 us; speedup 1.0000x reference)
//
#include <hip/hip_runtime.h>

// B=8, N1=8192, N2=2048, C1=128, C2=256, O1=O2=256, IN_CH=384
typedef __attribute__((ext_vector_type(8))) short bf16x8;
typedef __attribute__((ext_vector_type(4))) float f32x4;
typedef __attribute__((ext_vector_type(4))) unsigned short u16x4;

__device__ __forceinline__ unsigned short f2bf(float f) {
  unsigned u = __float_as_uint(f);
  u += 0x7FFFu + ((u >> 16) & 1u);   // RNE to bf16
  return (unsigned short)(u >> 16);
}

// ---------- prep: ft2(bf16 [b][n2][c]) + ft1(bf16 [b][n1][c]) + wpk + xyz2s --
__global__ __launch_bounds__(256) void prep(
    const float* __restrict__ f1, const float* __restrict__ f2,
    const float* __restrict__ xyz2,
    const float* __restrict__ W1, const float* __restrict__ W2,
    short* __restrict__ ft1, unsigned short* __restrict__ ft2,
    short* __restrict__ wpk1, short* __restrict__ wpk2,
    float4* __restrict__ xyz2s) {
  __shared__ float tile[64][65];
  const int bid = blockIdx.x, t = threadIdx.x;
  const int tj = t & 63, tr = t >> 6;
  if (bid < 1024) {          // feats2 [b][256][2048] f32 -> ft2 [b][2048][256] bf16
    int b = bid & 7, i = bid >> 3;
    int j0 = (i & 31) * 64, c0 = (i >> 5) * 64;
#pragma unroll
    for (int p = 0; p < 16; ++p) {
      int ci = p * 4 + tr;
      tile[ci][tj] = f2[(size_t)(b * 256 + c0 + ci) * 2048 + j0 + tj];
    }
    __syncthreads();
#pragma unroll
    for (int p = 0; p < 16; ++p) {
      int jr = p * 4 + tr;
      ft2[(size_t)(b * 2048 + j0 + jr) * 256 + c0 + tj] = f2bf(tile[tj][jr]);
    }
  } else if (bid < 3072) {   // feats1 [b][128][8192] f32 -> ft1 [b][8192][128] bf16
    int i = bid - 1024;
    int b = i & 7, ii = i >> 3;
    int j0 = (ii & 127) * 64, c0 = (ii >> 7) * 64;
#pragma unroll
    for (int p = 0; p < 16; ++p) {
      int ci = p * 4 + tr;
      tile[ci][tj] = f1[(size_t)(b * 128 + c0 + ci) * 8192 + j0 + tj];
    }
    __syncthreads();
#pragma unroll
    for (int p = 0; p < 16; ++p) {
      int jr = p * 4 + tr;
      ft1[((size_t)b * 8192 + j0 + jr) * 128 + c0 + tj] = (short)f2bf(tile[tj][jr]);
    }
  } else {                   // weight packing + candidate pack {x,y,z,|p|^2}
    int id = (bid - 3072) * 256 + t;           // 0..180223
    if (id < 98304) {                          // W1: K=384 -> 12 ktiles
      int j = id & 7, lane = (id >> 3) & 63, mt = (id >> 9) & 15, kt = id >> 13;
      int o = mt * 16 + (lane & 15);
      int c = kt * 32 + ((lane >> 4) & 3) * 8 + j;
      wpk1[id] = (short)f2bf(W1[o * 384 + c]);
    } else if (id < 163840) {                  // W2: K=256 -> 8 ktiles
      int f = id - 98304;
      int j = f & 7, lane = (f >> 3) & 63, mt = (f >> 9) & 15, kt = f >> 13;
      int o = mt * 16 + (lane & 15);
      int c = kt * 32 + ((lane >> 4) & 3) * 8 + j;
      wpk2[f] = (short)f2bf(W2[o * 256 + c]);
    } else {                                   // xyz2s: 16384 points
      int p = id - 163840;
      int b = p >> 11, j = p & 2047;
      const float* q = xyz2 + (size_t)(b * 2048 + j) * 3;
      float px = q[0], py = q[1], pz = q[2];
      float s2 = __fadd_rn(__fadd_rn(__fmul_rn(px, px), __fmul_rn(py, py)),
                           __fmul_rn(pz, pz));
      xyz2s[b * 2048 + j] = make_float4(px, py, pz, s2);
    }
  }
}

// ---------- 4-key ordered merge on packed f64 keys ---------------------------
__device__ __forceinline__ void merge44d(double a0, double a1, double a2, double a3,
                                         double c0, double c1, double c2, double c3,
                                         double& o0, double& o1, double& o2, double& o3) {
#define POP(OD)                                                           \
  {                                                                       \
    bool s = a0 < c0;                                                     \
    OD = s ? a0 : c0;                                                     \
    double sa0 = s ? a1 : a0, sa1 = s ? a2 : a1, sa2 = s ? a3 : a2;       \
    double sc0 = s ? c0 : c1, sc1 = s ? c1 : c2, sc2 = s ? c2 : c3;       \
    a3 = s ? 1e300 : a3; c3 = s ? c3 : 1e300;                             \
    a0 = sa0; a1 = sa1; a2 = sa2; c0 = sc0; c1 = sc1; c2 = sc2;           \
  }
  POP(o0) POP(o1) POP(o2) POP(o3)
#undef POP
}

// ---------- fused: KNN + interp + concat + 2x (GEMM+BN+ReLU) -----------------
// 1D grid 1024: b = blk&7 (XCD-pinned batch), tile = blk>>3 -> 64 queries.
// 512 threads (8 waves). LDS: XH 32KB (X-tile -> H1-tile) + T4 8KB (merge
// scratch -> W3/ID3) = 40960 B -> 4 blocks/CU, 32 waves/CU.
__global__ __launch_bounds__(512, 8) void fused(
    const float* __restrict__ xyz1, const float4* __restrict__ xyz2s,
    const unsigned short* __restrict__ ft2, const short* __restrict__ ft1,
    const short* __restrict__ wpk1, const short* __restrict__ wpk2,
    const float* __restrict__ b1, const float* __restrict__ g1, const float* __restrict__ be1,
    const float* __restrict__ b2, const float* __restrict__ g2, const float* __restrict__ be2,
    float* __restrict__ out) {
  __shared__ __align__(16) char XH[32768];
  __shared__ __align__(16) double T4[1024];
  float* W3s = (float*)((char*)T4 + 6144);    // 192 floats
  int*  ID3s = (int*)((char*)T4 + 6912);      // 192 ints (dead merge scratch)

  const int t = threadIdx.x, lane = t & 63, wid = t >> 6;
  const int blk = blockIdx.x;
  const int b = blk & 7, n0 = (blk >> 3) * 64;
  const int l15 = lane & 15, l4 = lane >> 4;

  // ---- query load (lane = query) ----
  float qx, qy, qz, s1;
  {
    const float* p = xyz1 + ((size_t)b * 8192 + n0 + lane) * 3;
    qx = p[0]; qy = p[1]; qz = p[2];
    s1 = __fadd_rn(__fadd_rn(__fmul_rn(qx, qx), __fmul_rn(qy, qy)), __fmul_rn(qz, qz));
  }

  // ---- phase 1: scan my 256-candidate segment (wave-uniform scalar stream).
  // u32 key = bits(max(d2,0)) with med3 insert + exact index chain
  // (strict-< stable: ties keep incumbent = earliest index).
  unsigned k0 = 0xFFFFFFFFu, k1 = 0xFFFFFFFFu, k2 = 0xFFFFFFFFu, k3 = 0xFFFFFFFFu;
  unsigned i0 = 0, i1 = 0, i2 = 0, i3 = 0;
  {
    const int jb = __builtin_amdgcn_readfirstlane(wid * 256);
    const float4* __restrict__ pk = xyz2s + (size_t)b * 2048;
#pragma unroll 4
    for (int jo = 0; jo < 256; ++jo) {
      int j = jb + jo;
      float4 P = pk[j];
      float dot = __fadd_rn(__fadd_rn(__fmul_rn(qx, P.x), __fmul_rn(qy, P.y)),
                            __fmul_rn(qz, P.z));
      float d2 = __fsub_rn(__fadd_rn(s1, P.w), __fadd_rn(dot, dot));
      unsigned K = __float_as_uint(fmaxf(d2, 0.0f));
      bool l0 = K < k0, l1 = K < k1, l2 = K < k2, l3 = K < k3;
      unsigned nk0 = min(k0, K);
      unsigned nk1 = min(max(K, k0), k1);     // med3(K,k0,k1)
      unsigned nk2 = min(max(K, k1), k2);
      unsigned nk3 = min(max(K, k2), k3);
      unsigned uj = (unsigned)j;
      unsigned ni0 = l0 ? uj : i0;
      unsigned ni1 = l0 ? i0 : (l1 ? uj : i1);
      unsigned ni2 = l1 ? i1 : (l2 ? uj : i2);
      unsigned ni3 = l2 ? i2 : (l3 ? uj : i3);
      k0 = nk0; k1 = nk1; k2 = nk2; k3 = nk3;
      i0 = ni0; i1 = ni1; i2 = ni2; i3 = ni3;
    }
  }
  // pack to exact f64 keys: key = d2bits*2048 + idx (exact, < 2^53)
  double key0 = fma((double)k0, 2048.0, (double)i0);
  double key1 = fma((double)k1, 2048.0, (double)i1);
  double key2 = fma((double)k2, 2048.0, (double)i2);
  double key3 = fma((double)k3, 2048.0, (double)i3);

  // ---- hierarchical cross-wave merge in 8KB scratch ----
  if (wid >= 4) {
    int w = wid - 4;
    T4[0 * 256 + w * 64 + lane] = key0; T4[1 * 256 + w * 64 + lane] = key1;
    T4[2 * 256 + w * 64 + lane] = key2; T4[3 * 256 + w * 64 + lane] = key3;
  }
  __syncthreads();
  double m10 = 0, m11 = 0, m12 = 0, m13 = 0;
  if (wid < 4) {
    double p0 = T4[0 * 256 + wid * 64 + lane], p1 = T4[1 * 256 + wid * 64 + lane];
    double p2 = T4[2 * 256 + wid * 64 + lane], p3 = T4[3 * 256 + wid * 64 + lane];
    merge44d(key0, key1, key2, key3, p0, p1, p2, p3, m10, m11, m12, m13);
  }
  __syncthreads();
  if (wid == 2 || wid == 3) {
    int w = wid - 2;
    T4[0 * 128 + w * 64 + lane] = m10; T4[1 * 128 + w * 64 + lane] = m11;
    T4[2 * 128 + w * 64 + lane] = m12; T4[3 * 128 + w * 64 + lane] = m13;
  }
  __syncthreads();
  double m20 = 0, m21 = 0, m22 = 0, m23 = 0;
  if (wid < 2) {
    double p0 = T4[0 * 128 + wid * 64 + lane], p1 = T4[1 * 128 + wid * 64 + lane];
    double p2 = T4[2 * 128 + wid * 64 + lane], p3 = T4[3 * 128 + wid * 64 + lane];
    merge44d(m10, m11, m12, m13, p0, p1, p2, p3, m20, m21, m22, m23);
  }
  __syncthreads();
  if (wid == 1) {
    T4[0 * 64 + lane] = m20; T4[1 * 64 + lane] = m21;
    T4[2 * 64 + lane] = m22; T4[3 * 64 + lane] = m23;
  }
  __syncthreads();
  if (wid == 0) {
    double p0 = T4[0 * 64 + lane], p1 = T4[1 * 64 + lane];
    double p2 = T4[2 * 64 + lane], p3 = T4[3 * 64 + lane];
    double mf[4];
    merge44d(m20, m21, m22, m23, p0, p1, p2, p3, mf[0], mf[1], mf[2], mf[3]);
    // unpack (exact): key = dcbits*2048 + j
    float e[4]; int ji[4];
#pragma unroll
    for (int s = 0; s < 4; ++s) {
      double qd = mf[s] * (1.0 / 2048.0);
      double qf = trunc(qd);
      double jd = fma(-qf, 2048.0, mf[s]);
      ji[s] = (int)jd;
      e[s] = __fsqrt_rn(__uint_as_float((unsigned)qf));
    }
    // stable (d, idx) sort over 4 (handles sqrt-collapse ties like np top_k)
#define SW(X, Y)                                                          \
  {                                                                       \
    bool sw = (e[X] > e[Y]) || ((e[X] == e[Y]) && (ji[X] > ji[Y]));       \
    float td = e[X]; int ti = ji[X];                                      \
    e[X] = sw ? e[Y] : e[X]; ji[X] = sw ? ji[Y] : ji[X];                  \
    e[Y] = sw ? td : e[Y];   ji[Y] = sw ? ti : ji[Y];                     \
  }
    SW(0, 1) SW(1, 2) SW(2, 3) SW(0, 1) SW(1, 2) SW(0, 1)
#undef SW
    float c0 = fmaxf(e[0], 1e-8f), c1 = fmaxf(e[1], 1e-8f), c2 = fmaxf(e[2], 1e-8f);
    float u0 = 1.0f / c0, u1 = 1.0f / c1, u2 = 1.0f / c2;
    float ss = __fadd_rn(__fadd_rn(u0, u1), u2);
    W3s[lane * 3 + 0] = u0 / ss; W3s[lane * 3 + 1] = u1 / ss; W3s[lane * 3 + 2] = u2 / ss;
    ID3s[lane * 3 + 0] = ji[0]; ID3s[lane * 3 + 1] = ji[1]; ID3s[lane * 3 + 2] = ji[2];
  }
  __syncthreads();

  // ---- phase 3: interpolation -> X-tile in XH (bf16 [64][256], XOR-swizzled)
  {
    const int c = t & 255, half = t >> 8;
    const size_t f2b = (size_t)b * 2048 * 256;
#pragma unroll 2
    for (int qi = 0; qi < 32; ++qi) {
      int q = half * 32 + qi;
      int j0 = ID3s[q * 3 + 0], j1 = ID3s[q * 3 + 1], j2 = ID3s[q * 3 + 2];
      float W0 = W3s[q * 3 + 0], W1v = W3s[q * 3 + 1], W2v = W3s[q * 3 + 2];
      float v0 = __uint_as_float((unsigned)ft2[f2b + (size_t)j0 * 256 + c] << 16);
      float v1 = __uint_as_float((unsigned)ft2[f2b + (size_t)j1 * 256 + c] << 16);
      float v2 = __uint_as_float((unsigned)ft2[f2b + (size_t)j2 * 256 + c] << 16);
      float v = W0 * v0 + W1v * v1 + W2v * v2;
      int addr = (q * 512 + c * 2) ^ ((q & 7) << 4);
      *(unsigned short*)(XH + addr) = f2bf(v);
    }
  }
  __syncthreads();

  // ---- phase 4: GEMM1 (K=384 = 256 interp from LDS + 128 feats1 from global)
  f32x4 acc[2][4];
#pragma unroll
  for (int m = 0; m < 2; ++m)
#pragma unroll
    for (int n = 0; n < 4; ++n) acc[m][n] = (f32x4){0.f, 0.f, 0.f, 0.f};

#pragma unroll
  for (int kt = 0; kt < 8; ++kt) {
    bf16x8 a[2], bb[4];
#pragma unroll
    for (int m = 0; m < 2; ++m)
      a[m] = *(const bf16x8*)(wpk1 + ((size_t)(kt * 16 + wid * 2 + m) * 64 + lane) * 8);
#pragma unroll
    for (int nt = 0; nt < 4; ++nt) {
      int q = nt * 16 + l15;
      int addr = q * 512 + ((kt * 64 + l4 * 16) ^ ((q & 7) << 4));
      bb[nt] = *(const bf16x8*)(XH + addr);
    }
#pragma unroll
    for (int m = 0; m < 2; ++m)
#pragma unroll
      for (int nt = 0; nt < 4; ++nt)
        acc[m][nt] = __builtin_amdgcn_mfma_f32_16x16x32_bf16(a[m], bb[nt], acc[m][nt], 0, 0, 0);
  }
#pragma unroll
  for (int kt = 8; kt < 12; ++kt) {
    bf16x8 a[2], bb[4];
#pragma unroll
    for (int m = 0; m < 2; ++m)
      a[m] = *(const bf16x8*)(wpk1 + ((size_t)(kt * 16 + wid * 2 + m) * 64 + lane) * 8);
#pragma unroll
    for (int nt = 0; nt < 4; ++nt)
      bb[nt] = *(const bf16x8*)(ft1 + ((size_t)b * 8192 + n0 + nt * 16 + l15) * 128 +
                                (kt - 8) * 32 + l4 * 8);
#pragma unroll
    for (int m = 0; m < 2; ++m)
#pragma unroll
      for (int nt = 0; nt < 4; ++nt)
        acc[m][nt] = __builtin_amdgcn_mfma_f32_16x16x32_bf16(a[m], bb[nt], acc[m][nt], 0, 0, 0);
  }
  __syncthreads();   // all reads of XH (X) complete before H1 overwrites it

  // ---- epilogue 1: H1 = relu(bn(acc+b1)) -> XH bf16 swizzled ----
  const float BNINV = 0.99999500003749972f;   // 1/sqrt(1+1e-5)
#pragma unroll
  for (int m = 0; m < 2; ++m) {
    int cb = wid * 32 + m * 16 + l4 * 4;
    float gv[4], bv[4], ev[4];
#pragma unroll
    for (int r = 0; r < 4; ++r) {
      gv[r] = g1[cb + r] * BNINV; bv[r] = b1[cb + r]; ev[r] = be1[cb + r];
    }
#pragma unroll
    for (int nt = 0; nt < 4; ++nt) {
      int q = nt * 16 + l15;
      u16x4 pk4;
#pragma unroll
      for (int r = 0; r < 4; ++r)
        pk4[r] = f2bf(fmaxf((acc[m][nt][r] + bv[r]) * gv[r] + ev[r], 0.0f));
      *(u16x4*)(XH + ((q * 512 + cb * 2) ^ ((q & 7) << 4))) = pk4;
    }
  }
  __syncthreads();

  // ---- phase 5: GEMM2 (K=256 from XH) ----
#pragma unroll
  for (int m = 0; m < 2; ++m)
#pragma unroll
    for (int n = 0; n < 4; ++n) acc[m][n] = (f32x4){0.f, 0.f, 0.f, 0.f};
#pragma unroll
  for (int kt = 0; kt < 8; ++kt) {
    bf16x8 a[2], bb[4];
#pragma unroll
    for (int m = 0; m < 2; ++m)
      a[m] = *(const bf16x8*)(wpk2 + ((size_t)(kt * 16 + wid * 2 + m) * 64 + lane) * 8);
#pragma unroll
    for (int nt = 0; nt < 4; ++nt) {
      int q = nt * 16 + l15;
      int addr = q * 512 + ((kt * 64 + l4 * 16) ^ ((q & 7) << 4));
      bb[nt] = *(const bf16x8*)(XH + addr);
    }
#pragma unroll
    for (int m = 0; m < 2; ++m)
#pragma unroll
      for (int nt = 0; nt < 4; ++nt)
        acc[m][nt] = __builtin_amdgcn_mfma_f32_16x16x32_bf16(a[m], bb[nt], acc[m][nt], 0, 0, 0);
  }

  // ---- epilogue 2: out = relu(bn(acc+b2)) -> d_out f32 [b][o][n] ----
#pragma unroll
  for (int m = 0; m < 2; ++m) {
    int ob = wid * 32 + m * 16 + l4 * 4;
    float gv[4], bv[4], ev[4];
#pragma unroll
    for (int r = 0; r < 4; ++r) {
      gv[r] = g2[ob + r] * BNINV; bv[r] = b2[ob + r]; ev[r] = be2[ob + r];
    }
#pragma unroll
    for (int nt = 0; nt < 4; ++nt) {
      int nn = n0 + nt * 16 + l15;
#pragma unroll
      for (int r = 0; r < 4; ++r)
        out[((size_t)b * 256 + ob + r) * 8192 + nn] =
            fmaxf((acc[m][nt][r] + bv[r]) * gv[r] + ev[r], 0.0f);
    }
  }
}

extern "C" void kernel_launch(void* const* d_in, const int* in_sizes, int n_in,
                              void* d_out, int out_size, void* d_ws, size_t ws_size,
                              hipStream_t stream) {
  (void)in_sizes; (void)n_in; (void)out_size; (void)ws_size;
  const float* xyz1   = (const float*)d_in[0];
  const float* xyz2   = (const float*)d_in[1];
  const float* feats1 = (const float*)d_in[2];
  const float* feats2 = (const float*)d_in[3];
  const float* W1  = (const float*)d_in[4];
  const float* b1  = (const float*)d_in[5];
  const float* g1  = (const float*)d_in[6];
  const float* be1 = (const float*)d_in[7];
  const float* W2  = (const float*)d_in[8];
  const float* b2  = (const float*)d_in[9];
  const float* g2  = (const float*)d_in[10];
  const float* be2 = (const float*)d_in[11];
  float* out = (float*)d_out;

  // ws layout (25,755,648 B):
  //   [0,       196608)    wpk1 bf16
  //   [196608,  327680)    wpk2 bf16
  //   [327680,  589824)    xyz2s float4 [8][2048]
  //   [589824,  8978432)   ft2 bf16 [8][2048][256]
  //   [8978432, 25755648)  ft1 bf16 [8][8192][128]
  char* ws = (char*)d_ws;
  short*          wpk1  = (short*)(ws);
  short*          wpk2  = (short*)(ws + 196608);
  float4*         xyz2s = (float4*)(ws + 327680);
  unsigned short* ft2   = (unsigned short*)(ws + 589824);
  short*          ft1   = (short*)(ws + 8978432);

  prep<<<3776, 256, 0, stream>>>(feats1, feats2, xyz2, W1, W2,
                                 ft1, ft2, wpk1, wpk2, xyz2s);
  fused<<<1024, 512, 0, stream>>>(xyz1, xyz2s, ft2, ft1, wpk1, wpk2,
                                  b1, g1, be1, b2, g2, be2, out);
}

// Round 5
// 249.682 us; speedup vs baseline: 1.0695x; 1.0695x over previous
//
#include <hip/hip_runtime.h>

// B=8, N1=8192, N2=2048, C1=128, C2=256, O1=O2=256, IN_CH=384
typedef __attribute__((ext_vector_type(8))) short bf16x8;
typedef __attribute__((ext_vector_type(4))) float f32x4;
typedef __attribute__((ext_vector_type(4))) unsigned short u16x4;

__device__ __forceinline__ unsigned short f2bf(float f) {
  unsigned u = __float_as_uint(f);
  u += 0x7FFFu + ((u >> 16) & 1u);   // RNE to bf16
  return (unsigned short)(u >> 16);
}

// ---------- prep: ft2(bf16 [b][n2][c]) + ft1(bf16 [b][n1][c]) + wpk + xyz2s --
// Transposes use float4 loads + u16x4 stores (4x fewer mem instructions).
__global__ __launch_bounds__(256) void prep(
    const float* __restrict__ f1, const float* __restrict__ f2,
    const float* __restrict__ xyz2,
    const float* __restrict__ W1, const float* __restrict__ W2,
    short* __restrict__ ft1, unsigned short* __restrict__ ft2,
    short* __restrict__ wpk1, short* __restrict__ wpk2,
    float4* __restrict__ xyz2s) {
  __shared__ float tile[64][65];
  const int bid = blockIdx.x, t = threadIdx.x;
  if (bid < 1024) {          // feats2 [b][256][2048] f32 -> ft2 [b][2048][256] bf16
    int b = bid & 7, i = bid >> 3;
    int j0 = (i & 31) * 64, c0 = (i >> 5) * 64;
    int r = t >> 4, c4 = (t & 15) * 4;         // 16 rows/pass x 16 lanes x float4
#pragma unroll
    for (int p = 0; p < 4; ++p) {
      int ci = p * 16 + r;
      float4 v = *(const float4*)&f2[(size_t)(b * 256 + c0 + ci) * 2048 + j0 + c4];
      tile[ci][c4] = v.x; tile[ci][c4 + 1] = v.y;
      tile[ci][c4 + 2] = v.z; tile[ci][c4 + 3] = v.w;
    }
    __syncthreads();
#pragma unroll
    for (int p = 0; p < 4; ++p) {
      int jr = p * 16 + r;
      u16x4 o;
#pragma unroll
      for (int k = 0; k < 4; ++k) o[k] = f2bf(tile[c4 + k][jr]);
      *(u16x4*)&ft2[(size_t)(b * 2048 + j0 + jr) * 256 + c0 + c4] = o;
    }
  } else if (bid < 3072) {   // feats1 [b][128][8192] f32 -> ft1 [b][8192][128] bf16
    int i = bid - 1024;
    int b = i & 7, ii = i >> 3;
    int j0 = (ii & 127) * 64, c0 = (ii >> 7) * 64;
    int r = t >> 4, c4 = (t & 15) * 4;
#pragma unroll
    for (int p = 0; p < 4; ++p) {
      int ci = p * 16 + r;
      float4 v = *(const float4*)&f1[(size_t)(b * 128 + c0 + ci) * 8192 + j0 + c4];
      tile[ci][c4] = v.x; tile[ci][c4 + 1] = v.y;
      tile[ci][c4 + 2] = v.z; tile[ci][c4 + 3] = v.w;
    }
    __syncthreads();
#pragma unroll
    for (int p = 0; p < 4; ++p) {
      int jr = p * 16 + r;
      u16x4 o;
#pragma unroll
      for (int k = 0; k < 4; ++k) o[k] = f2bf(tile[c4 + k][jr]);
      *(u16x4*)&ft1[((size_t)b * 8192 + j0 + jr) * 128 + c0 + c4] = o;
    }
  } else {                   // weight packing + candidate pack {x,y,z,|p|^2}
    int id = (bid - 3072) * 256 + t;           // 0..180223
    if (id < 98304) {                          // W1: K=384 -> 12 ktiles
      int j = id & 7, lane = (id >> 3) & 63, mt = (id >> 9) & 15, kt = id >> 13;
      int o = mt * 16 + (lane & 15);
      int c = kt * 32 + ((lane >> 4) & 3) * 8 + j;
      wpk1[id] = (short)f2bf(W1[o * 384 + c]);
    } else if (id < 163840) {                  // W2: K=256 -> 8 ktiles
      int f = id - 98304;
      int j = f & 7, lane = (f >> 3) & 63, mt = (f >> 9) & 15, kt = f >> 13;
      int o = mt * 16 + (lane & 15);
      int c = kt * 32 + ((lane >> 4) & 3) * 8 + j;
      wpk2[f] = (short)f2bf(W2[o * 256 + c]);
    } else {                                   // xyz2s: 16384 points
      int p = id - 163840;
      int b = p >> 11, j = p & 2047;
      const float* q = xyz2 + (size_t)(b * 2048 + j) * 3;
      float px = q[0], py = q[1], pz = q[2];
      float s2 = __fadd_rn(__fadd_rn(__fmul_rn(px, px), __fmul_rn(py, py)),
                           __fmul_rn(pz, pz));
      xyz2s[b * 2048 + j] = make_float4(px, py, pz, s2);
    }
  }
}

// ---------- 4-key ordered merge on packed f64 keys ---------------------------
__device__ __forceinline__ void merge44d(double a0, double a1, double a2, double a3,
                                         double c0, double c1, double c2, double c3,
                                         double& o0, double& o1, double& o2, double& o3) {
#define POP(OD)                                                           \
  {                                                                       \
    bool s = a0 < c0;                                                     \
    OD = s ? a0 : c0;                                                     \
    double sa0 = s ? a1 : a0, sa1 = s ? a2 : a1, sa2 = s ? a3 : a2;       \
    double sc0 = s ? c0 : c1, sc1 = s ? c1 : c2, sc2 = s ? c2 : c3;       \
    a3 = s ? 1e300 : a3; c3 = s ? c3 : 1e300;                             \
    a0 = sa0; a1 = sa1; a2 = sa2; c0 = sc0; c1 = sc1; c2 = sc2;           \
  }
  POP(o0) POP(o1) POP(o2) POP(o3)
#undef POP
}

// ---------- fused: KNN + interp + concat + 2x (GEMM+BN+ReLU) -----------------
// 1D grid 1024: b = blk&7 (XCD-pinned batch), tile = blk>>3 -> 64 queries.
// 512 threads (8 waves). LDS: XH 32KB (candidates -> X-tile -> H1-tile) +
// T4 8KB (merge scratch -> W3/ID3) = 40960 B -> 4 blocks/CU by LDS.
__global__ __launch_bounds__(512) void fused(
    const float* __restrict__ xyz1, const float4* __restrict__ xyz2s,
    const unsigned short* __restrict__ ft2, const short* __restrict__ ft1,
    const short* __restrict__ wpk1, const short* __restrict__ wpk2,
    const float* __restrict__ b1, const float* __restrict__ g1, const float* __restrict__ be1,
    const float* __restrict__ b2, const float* __restrict__ g2, const float* __restrict__ be2,
    float* __restrict__ out) {
  __shared__ __align__(16) char XH[32768];
  __shared__ __align__(16) double T4[1024];
  float* W3s = (float*)((char*)T4 + 6144);    // 192 floats
  int*  ID3s = (int*)((char*)T4 + 6912);      // 192 ints (dead merge scratch)

  const int t = threadIdx.x, lane = t & 63, wid = t >> 6;
  const int blk = blockIdx.x;
  const int b = blk & 7, n0 = (blk >> 3) * 64;
  const int l15 = lane & 15, l4 = lane >> 4;

  // ---- phase 0: stage candidates {x,y,z,|p|^2} into XH; load queries ----
  {
    float4* pkB = (float4*)XH;
    for (int j = t; j < 2048; j += 512) pkB[j] = xyz2s[b * 2048 + j];
  }
  float qx, qy, qz, s1;
  {
    const float* p = xyz1 + ((size_t)b * 8192 + n0 + lane) * 3;
    qx = p[0]; qy = p[1]; qz = p[2];
    s1 = __fadd_rn(__fadd_rn(__fmul_rn(qx, qx), __fmul_rn(qy, qy)), __fmul_rn(qz, qz));
  }
  __syncthreads();

  // ---- phase 1: scan my 256-candidate segment (LDS broadcast reads).
  // u32 key = bits(max(d2,0)); med3 insert + exact index chain
  // (strict-<: ties keep incumbent = earliest index; j ascending).
  unsigned k0 = 0xFFFFFFFFu, k1 = 0xFFFFFFFFu, k2 = 0xFFFFFFFFu, k3 = 0xFFFFFFFFu;
  unsigned i0 = 0, i1 = 0, i2 = 0, i3 = 0;
  {
    const float4* __restrict__ pkB = (const float4*)XH;
    const int jb = wid * 256;
#pragma unroll 4
    for (int jo = 0; jo < 256; ++jo) {
      int j = jb + jo;
      float4 P = pkB[j];
      float dot = __fadd_rn(__fadd_rn(__fmul_rn(qx, P.x), __fmul_rn(qy, P.y)),
                            __fmul_rn(qz, P.z));
      float d2 = __fsub_rn(__fadd_rn(s1, P.w), __fadd_rn(dot, dot));
      unsigned K = __float_as_uint(fmaxf(d2, 0.0f));
      bool l0 = K < k0, l1 = K < k1, l2 = K < k2, l3 = K < k3;
      unsigned nk0 = min(k0, K);
      unsigned nk1 = min(max(K, k0), k1);     // med3(K,k0,k1)
      unsigned nk2 = min(max(K, k1), k2);
      unsigned nk3 = min(max(K, k2), k3);
      unsigned uj = (unsigned)j;
      unsigned ni0 = l0 ? uj : i0;
      unsigned ni1 = l0 ? i0 : (l1 ? uj : i1);
      unsigned ni2 = l1 ? i1 : (l2 ? uj : i2);
      unsigned ni3 = l2 ? i2 : (l3 ? uj : i3);
      k0 = nk0; k1 = nk1; k2 = nk2; k3 = nk3;
      i0 = ni0; i1 = ni1; i2 = ni2; i3 = ni3;
    }
  }
  // pack to exact f64 keys: key = d2bits*2048 + idx (exact, < 2^53)
  double key0 = fma((double)k0, 2048.0, (double)i0);
  double key1 = fma((double)k1, 2048.0, (double)i1);
  double key2 = fma((double)k2, 2048.0, (double)i2);
  double key3 = fma((double)k3, 2048.0, (double)i3);

  // ---- hierarchical cross-wave merge in 8KB scratch ----
  if (wid >= 4) {
    int w = wid - 4;
    T4[0 * 256 + w * 64 + lane] = key0; T4[1 * 256 + w * 64 + lane] = key1;
    T4[2 * 256 + w * 64 + lane] = key2; T4[3 * 256 + w * 64 + lane] = key3;
  }
  __syncthreads();
  double m10 = 0, m11 = 0, m12 = 0, m13 = 0;
  if (wid < 4) {
    double p0 = T4[0 * 256 + wid * 64 + lane], p1 = T4[1 * 256 + wid * 64 + lane];
    double p2 = T4[2 * 256 + wid * 64 + lane], p3 = T4[3 * 256 + wid * 64 + lane];
    merge44d(key0, key1, key2, key3, p0, p1, p2, p3, m10, m11, m12, m13);
  }
  __syncthreads();
  if (wid == 2 || wid == 3) {
    int w = wid - 2;
    T4[0 * 128 + w * 64 + lane] = m10; T4[1 * 128 + w * 64 + lane] = m11;
    T4[2 * 128 + w * 64 + lane] = m12; T4[3 * 128 + w * 64 + lane] = m13;
  }
  __syncthreads();
  double m20 = 0, m21 = 0, m22 = 0, m23 = 0;
  if (wid < 2) {
    double p0 = T4[0 * 128 + wid * 64 + lane], p1 = T4[1 * 128 + wid * 64 + lane];
    double p2 = T4[2 * 128 + wid * 64 + lane], p3 = T4[3 * 128 + wid * 64 + lane];
    merge44d(m10, m11, m12, m13, p0, p1, p2, p3, m20, m21, m22, m23);
  }
  __syncthreads();
  if (wid == 1) {
    T4[0 * 64 + lane] = m20; T4[1 * 64 + lane] = m21;
    T4[2 * 64 + lane] = m22; T4[3 * 64 + lane] = m23;
  }
  __syncthreads();
  if (wid == 0) {
    double p0 = T4[0 * 64 + lane], p1 = T4[1 * 64 + lane];
    double p2 = T4[2 * 64 + lane], p3 = T4[3 * 64 + lane];
    double mf[4];
    merge44d(m20, m21, m22, m23, p0, p1, p2, p3, mf[0], mf[1], mf[2], mf[3]);
    // unpack (exact): key = dcbits*2048 + j
    float e[4]; int ji[4];
#pragma unroll
    for (int s = 0; s < 4; ++s) {
      double qd = mf[s] * (1.0 / 2048.0);
      double qf = trunc(qd);
      double jd = fma(-qf, 2048.0, mf[s]);
      ji[s] = (int)jd;
      e[s] = __fsqrt_rn(__uint_as_float((unsigned)qf));
    }
    // stable (d, idx) sort over 4 (handles sqrt-collapse ties like np top_k)
#define SW(X, Y)                                                          \
  {                                                                       \
    bool sw = (e[X] > e[Y]) || ((e[X] == e[Y]) && (ji[X] > ji[Y]));       \
    float td = e[X]; int ti = ji[X];                                      \
    e[X] = sw ? e[Y] : e[X]; ji[X] = sw ? ji[Y] : ji[X];                  \
    e[Y] = sw ? td : e[Y];   ji[Y] = sw ? ti : ji[Y];                     \
  }
    SW(0, 1) SW(1, 2) SW(2, 3) SW(0, 1) SW(1, 2) SW(0, 1)
#undef SW
    float c0 = fmaxf(e[0], 1e-8f), c1 = fmaxf(e[1], 1e-8f), c2 = fmaxf(e[2], 1e-8f);
    float u0 = 1.0f / c0, u1 = 1.0f / c1, u2 = 1.0f / c2;
    float ss = __fadd_rn(__fadd_rn(u0, u1), u2);
    W3s[lane * 3 + 0] = u0 / ss; W3s[lane * 3 + 1] = u1 / ss; W3s[lane * 3 + 2] = u2 / ss;
    ID3s[lane * 3 + 0] = ji[0]; ID3s[lane * 3 + 1] = ji[1]; ID3s[lane * 3 + 2] = ji[2];
  }
  __syncthreads();

  // ---- phase 3: interpolation -> X-tile in XH (bf16 [64][256], XOR-swizzled)
  {
    const int c = t & 255, half = t >> 8;
    const size_t f2b = (size_t)b * 2048 * 256;
#pragma unroll 2
    for (int qi = 0; qi < 32; ++qi) {
      int q = half * 32 + qi;
      int j0 = ID3s[q * 3 + 0], j1 = ID3s[q * 3 + 1], j2 = ID3s[q * 3 + 2];
      float W0 = W3s[q * 3 + 0], W1v = W3s[q * 3 + 1], W2v = W3s[q * 3 + 2];
      float v0 = __uint_as_float((unsigned)ft2[f2b + (size_t)j0 * 256 + c] << 16);
      float v1 = __uint_as_float((unsigned)ft2[f2b + (size_t)j1 * 256 + c] << 16);
      float v2 = __uint_as_float((unsigned)ft2[f2b + (size_t)j2 * 256 + c] << 16);
      float v = W0 * v0 + W1v * v1 + W2v * v2;
      int addr = (q * 512 + c * 2) ^ ((q & 7) << 4);
      *(unsigned short*)(XH + addr) = f2bf(v);
    }
  }
  __syncthreads();

  // ---- phase 4: GEMM1 (K=384 = 256 interp from LDS + 128 feats1 from global)
  f32x4 acc[2][4];
#pragma unroll
  for (int m = 0; m < 2; ++m)
#pragma unroll
    for (int n = 0; n < 4; ++n) acc[m][n] = (f32x4){0.f, 0.f, 0.f, 0.f};

#pragma unroll
  for (int kt = 0; kt < 8; ++kt) {
    bf16x8 a[2], bb[4];
#pragma unroll
    for (int m = 0; m < 2; ++m)
      a[m] = *(const bf16x8*)(wpk1 + ((size_t)(kt * 16 + wid * 2 + m) * 64 + lane) * 8);
#pragma unroll
    for (int nt = 0; nt < 4; ++nt) {
      int q = nt * 16 + l15;
      int addr = q * 512 + ((kt * 64 + l4 * 16) ^ ((q & 7) << 4));
      bb[nt] = *(const bf16x8*)(XH + addr);
    }
#pragma unroll
    for (int m = 0; m < 2; ++m)
#pragma unroll
      for (int nt = 0; nt < 4; ++nt)
        acc[m][nt] = __builtin_amdgcn_mfma_f32_16x16x32_bf16(a[m], bb[nt], acc[m][nt], 0, 0, 0);
  }
#pragma unroll
  for (int kt = 8; kt < 12; ++kt) {
    bf16x8 a[2], bb[4];
#pragma unroll
    for (int m = 0; m < 2; ++m)
      a[m] = *(const bf16x8*)(wpk1 + ((size_t)(kt * 16 + wid * 2 + m) * 64 + lane) * 8);
#pragma unroll
    for (int nt = 0; nt < 4; ++nt)
      bb[nt] = *(const bf16x8*)(ft1 + ((size_t)b * 8192 + n0 + nt * 16 + l15) * 128 +
                                (kt - 8) * 32 + l4 * 8);
#pragma unroll
    for (int m = 0; m < 2; ++m)
#pragma unroll
      for (int nt = 0; nt < 4; ++nt)
        acc[m][nt] = __builtin_amdgcn_mfma_f32_16x16x32_bf16(a[m], bb[nt], acc[m][nt], 0, 0, 0);
  }
  __syncthreads();   // all reads of XH (X) complete before H1 overwrites it

  // ---- epilogue 1: H1 = relu(bn(acc+b1)) -> XH bf16 swizzled ----
  const float BNINV = 0.99999500003749972f;   // 1/sqrt(1+1e-5)
#pragma unroll
  for (int m = 0; m < 2; ++m) {
    int cb = wid * 32 + m * 16 + l4 * 4;
    float gv[4], bv[4], ev[4];
#pragma unroll
    for (int r = 0; r < 4; ++r) {
      gv[r] = g1[cb + r] * BNINV; bv[r] = b1[cb + r]; ev[r] = be1[cb + r];
    }
#pragma unroll
    for (int nt = 0; nt < 4; ++nt) {
      int q = nt * 16 + l15;
      u16x4 pk4;
#pragma unroll
      for (int r = 0; r < 4; ++r)
        pk4[r] = f2bf(fmaxf((acc[m][nt][r] + bv[r]) * gv[r] + ev[r], 0.0f));
      *(u16x4*)(XH + ((q * 512 + cb * 2) ^ ((q & 7) << 4))) = pk4;
    }
  }
  __syncthreads();

  // ---- phase 5: GEMM2 (K=256 from XH) ----
#pragma unroll
  for (int m = 0; m < 2; ++m)
#pragma unroll
    for (int n = 0; n < 4; ++n) acc[m][n] = (f32x4){0.f, 0.f, 0.f, 0.f};
#pragma unroll
  for (int kt = 0; kt < 8; ++kt) {
    bf16x8 a[2], bb[4];
#pragma unroll
    for (int m = 0; m < 2; ++m)
      a[m] = *(const bf16x8*)(wpk2 + ((size_t)(kt * 16 + wid * 2 + m) * 64 + lane) * 8);
#pragma unroll
    for (int nt = 0; nt < 4; ++nt) {
      int q = nt * 16 + l15;
      int addr = q * 512 + ((kt * 64 + l4 * 16) ^ ((q & 7) << 4));
      bb[nt] = *(const bf16x8*)(XH + addr);
    }
#pragma unroll
    for (int m = 0; m < 2; ++m)
#pragma unroll
      for (int nt = 0; nt < 4; ++nt)
        acc[m][nt] = __builtin_amdgcn_mfma_f32_16x16x32_bf16(a[m], bb[nt], acc[m][nt], 0, 0, 0);
  }

  // ---- epilogue 2: out = relu(bn(acc+b2)) -> d_out f32 [b][o][n] ----
#pragma unroll
  for (int m = 0; m < 2; ++m) {
    int ob = wid * 32 + m * 16 + l4 * 4;
    float gv[4], bv[4], ev[4];
#pragma unroll
    for (int r = 0; r < 4; ++r) {
      gv[r] = g2[ob + r] * BNINV; bv[r] = b2[ob + r]; ev[r] = be2[ob + r];
    }
#pragma unroll
    for (int nt = 0; nt < 4; ++nt) {
      int nn = n0 + nt * 16 + l15;
#pragma unroll
      for (int r = 0; r < 4; ++r)
        out[((size_t)b * 256 + ob + r) * 8192 + nn] =
            fmaxf((acc[m][nt][r] + bv[r]) * gv[r] + ev[r], 0.0f);
    }
  }
}

extern "C" void kernel_launch(void* const* d_in, const int* in_sizes, int n_in,
                              void* d_out, int out_size, void* d_ws, size_t ws_size,
                              hipStream_t stream) {
  (void)in_sizes; (void)n_in; (void)out_size; (void)ws_size;
  const float* xyz1   = (const float*)d_in[0];
  const float* xyz2   = (const float*)d_in[1];
  const float* feats1 = (const float*)d_in[2];
  const float* feats2 = (const float*)d_in[3];
  const float* W1  = (const float*)d_in[4];
  const float* b1  = (const float*)d_in[5];
  const float* g1  = (const float*)d_in[6];
  const float* be1 = (const float*)d_in[7];
  const float* W2  = (const float*)d_in[8];
  const float* b2  = (const float*)d_in[9];
  const float* g2  = (const float*)d_in[10];
  const float* be2 = (const float*)d_in[11];
  float* out = (float*)d_out;

  // ws layout (25,755,648 B):
  //   [0,       196608)    wpk1 bf16
  //   [196608,  327680)    wpk2 bf16
  //   [327680,  589824)    xyz2s float4 [8][2048]
  //   [589824,  8978432)   ft2 bf16 [8][2048][256]
  //   [8978432, 25755648)  ft1 bf16 [8][8192][128]
  char* ws = (char*)d_ws;
  short*          wpk1  = (short*)(ws);
  short*          wpk2  = (short*)(ws + 196608);
  float4*         xyz2s = (float4*)(ws + 327680);
  unsigned short* ft2   = (unsigned short*)(ws + 589824);
  short*          ft1   = (short*)(ws + 8978432);

  prep<<<3776, 256, 0, stream>>>(feats1, feats2, xyz2, W1, W2,
                                 ft1, ft2, wpk1, wpk2, xyz2s);
  fused<<<1024, 512, 0, stream>>>(xyz1, xyz2s, ft2, ft1, wpk1, wpk2,
                                  b1, g1, be1, b2, g2, be2, out);
}

// Round 6
// 230.086 us; speedup vs baseline: 1.1605x; 1.0852x over previous
//
#include <hip/hip_runtime.h>

// B=8, N1=8192, N2=2048, C1=128, C2=256, O1=O2=256, IN_CH=384
typedef __attribute__((ext_vector_type(8))) short bf16x8;
typedef __attribute__((ext_vector_type(4))) float f32x4;
typedef __attribute__((ext_vector_type(4))) unsigned short u16x4;

__device__ __forceinline__ unsigned short f2bf(float f) {
  unsigned u = __float_as_uint(f);
  u += 0x7FFFu + ((u >> 16) & 1u);   // RNE to bf16
  return (unsigned short)(u >> 16);
}

__device__ __forceinline__ unsigned med3u(unsigned a, unsigned b, unsigned c) {
  unsigned r;
  asm("v_med3_u32 %0, %1, %2, %3" : "=v"(r) : "v"(a), "v"(b), "v"(c));
  return r;
}

// ---------- prep: ft2(bf16 [b][n2][c]) + ft1(bf16 [b][n1][c]) + wpk + xyz2s --
__global__ __launch_bounds__(256) void prep(
    const float* __restrict__ f1, const float* __restrict__ f2,
    const float* __restrict__ xyz2,
    const float* __restrict__ W1, const float* __restrict__ W2,
    short* __restrict__ ft1, unsigned short* __restrict__ ft2,
    short* __restrict__ wpk1, short* __restrict__ wpk2,
    float4* __restrict__ xyz2s) {
  __shared__ float tile[64][65];
  const int bid = blockIdx.x, t = threadIdx.x;
  if (bid < 1024) {          // feats2 [b][256][2048] f32 -> ft2 [b][2048][256] bf16
    int b = bid & 7, i = bid >> 3;
    int j0 = (i & 31) * 64, c0 = (i >> 5) * 64;
    int r = t >> 4, c4 = (t & 15) * 4;
#pragma unroll
    for (int p = 0; p < 4; ++p) {
      int ci = p * 16 + r;
      float4 v = *(const float4*)&f2[(size_t)(b * 256 + c0 + ci) * 2048 + j0 + c4];
      tile[ci][c4] = v.x; tile[ci][c4 + 1] = v.y;
      tile[ci][c4 + 2] = v.z; tile[ci][c4 + 3] = v.w;
    }
    __syncthreads();
#pragma unroll
    for (int p = 0; p < 4; ++p) {
      int jr = p * 16 + r;
      u16x4 o;
#pragma unroll
      for (int k = 0; k < 4; ++k) o[k] = f2bf(tile[c4 + k][jr]);
      *(u16x4*)&ft2[(size_t)(b * 2048 + j0 + jr) * 256 + c0 + c4] = o;
    }
  } else if (bid < 3072) {   // feats1 [b][128][8192] f32 -> ft1 [b][8192][128] bf16
    int i = bid - 1024;
    int b = i & 7, ii = i >> 3;
    int j0 = (ii & 127) * 64, c0 = (ii >> 7) * 64;
    int r = t >> 4, c4 = (t & 15) * 4;
#pragma unroll
    for (int p = 0; p < 4; ++p) {
      int ci = p * 16 + r;
      float4 v = *(const float4*)&f1[(size_t)(b * 128 + c0 + ci) * 8192 + j0 + c4];
      tile[ci][c4] = v.x; tile[ci][c4 + 1] = v.y;
      tile[ci][c4 + 2] = v.z; tile[ci][c4 + 3] = v.w;
    }
    __syncthreads();
#pragma unroll
    for (int p = 0; p < 4; ++p) {
      int jr = p * 16 + r;
      u16x4 o;
#pragma unroll
      for (int k = 0; k < 4; ++k) o[k] = f2bf(tile[c4 + k][jr]);
      *(u16x4*)&ft1[((size_t)b * 8192 + j0 + jr) * 128 + c0 + c4] = o;
    }
  } else {                   // weight packing + candidate pack {x,y,z,|p|^2}
    int id = (bid - 3072) * 256 + t;           // 0..180223
    if (id < 98304) {                          // W1: K=384 -> 12 ktiles
      int j = id & 7, lane = (id >> 3) & 63, mt = (id >> 9) & 15, kt = id >> 13;
      int o = mt * 16 + (lane & 15);
      int c = kt * 32 + ((lane >> 4) & 3) * 8 + j;
      wpk1[id] = (short)f2bf(W1[o * 384 + c]);
    } else if (id < 163840) {                  // W2: K=256 -> 8 ktiles
      int f = id - 98304;
      int j = f & 7, lane = (f >> 3) & 63, mt = (f >> 9) & 15, kt = f >> 13;
      int o = mt * 16 + (lane & 15);
      int c = kt * 32 + ((lane >> 4) & 3) * 8 + j;
      wpk2[f] = (short)f2bf(W2[o * 256 + c]);
    } else {                                   // xyz2s: 16384 points
      int p = id - 163840;
      int b = p >> 11, j = p & 2047;
      const float* q = xyz2 + (size_t)(b * 2048 + j) * 3;
      float px = q[0], py = q[1], pz = q[2];
      float s2 = __fadd_rn(__fadd_rn(__fmul_rn(px, px), __fmul_rn(py, py)),
                           __fmul_rn(pz, pz));
      xyz2s[b * 2048 + j] = make_float4(px, py, pz, s2);
    }
  }
}

// ---------- sorted-8 u32 merge: keep 8 smallest of two ascending lists -------
__device__ __forceinline__ void ceu(unsigned& x, unsigned& y) {
  unsigned lo = min(x, y), hi = max(x, y);
  x = lo; y = hi;
}
__device__ __forceinline__ void merge8(unsigned k[8], const unsigned p[8]) {
  unsigned m0 = min(k[0], p[7]), m1 = min(k[1], p[6]);
  unsigned m2 = min(k[2], p[5]), m3 = min(k[3], p[4]);
  unsigned m4 = min(k[4], p[3]), m5 = min(k[5], p[2]);
  unsigned m6 = min(k[6], p[1]), m7 = min(k[7], p[0]);
  // bitonic sort of 8 (half-cleaner stages 4,2,1)
  ceu(m0, m4); ceu(m1, m5); ceu(m2, m6); ceu(m3, m7);
  ceu(m0, m2); ceu(m1, m3); ceu(m4, m6); ceu(m5, m7);
  ceu(m0, m1); ceu(m2, m3); ceu(m4, m5); ceu(m6, m7);
  k[0] = m0; k[1] = m1; k[2] = m2; k[3] = m3;
  k[4] = m4; k[5] = m5; k[6] = m6; k[7] = m7;
}

// ---------- fused: KNN + interp + concat + 2x (GEMM+BN+ReLU) -----------------
// 1D grid 1024: b = blk&7 (XCD-pinned batch), tile = blk>>3 -> 64 queries.
// 512 threads (8 waves). LDS: XH 32KB (merge scratch -> X-tile -> H1-tile) +
// W3s/ID3s 1.5KB = 34.3KB.
__global__ __launch_bounds__(512) void fused(
    const float* __restrict__ xyz1, const float4* __restrict__ xyz2s,
    const unsigned short* __restrict__ ft2, const short* __restrict__ ft1,
    const short* __restrict__ wpk1, const short* __restrict__ wpk2,
    const float* __restrict__ b1, const float* __restrict__ g1, const float* __restrict__ be1,
    const float* __restrict__ b2, const float* __restrict__ g2, const float* __restrict__ be2,
    float* __restrict__ out) {
  __shared__ __align__(16) char XH[32768];
  __shared__ float W3s[192];
  __shared__ int   ID3s[192];
  unsigned* MG = (unsigned*)XH;   // merge scratch (dead before X-tile is written)

  const int t = threadIdx.x, lane = t & 63, wid = t >> 6;
  const int blk = blockIdx.x;
  const int b = blk & 7, n0 = (blk >> 3) * 64;
  const int l15 = lane & 15, l4 = lane >> 4;

  // ---- query load (lane = query) ----
  float qx, qy, qz, s1;
  {
    const float* p = xyz1 + ((size_t)b * 8192 + n0 + lane) * 3;
    qx = p[0]; qy = p[1]; qz = p[2];
    s1 = __fadd_rn(__fadd_rn(__fmul_rn(qx, qx), __fmul_rn(qy, qy)), __fmul_rn(qz, qz));
  }

  // ---- phase 1: scan my 256-candidate segment from global (wave-uniform
  // stream, no LDS). key = (d2bits & ~0x7FF) | j : top-8 via med3 insert.
  unsigned k[8];
#pragma unroll
  for (int s = 0; s < 8; ++s) k[s] = 0xFFFFFFFFu;
  {
    const float4* __restrict__ pk = xyz2s + (size_t)b * 2048;
    const int jb = __builtin_amdgcn_readfirstlane(wid * 256);
#pragma unroll 4
    for (int jo = 0; jo < 256; ++jo) {
      int j = jb + jo;
      float4 P = pk[j];
      float dot = __fadd_rn(__fadd_rn(__fmul_rn(qx, P.x), __fmul_rn(qy, P.y)),
                            __fmul_rn(qz, P.z));
      float d2 = __fsub_rn(__fadd_rn(s1, P.w), __fadd_rn(dot, dot));
      unsigned K = (__float_as_uint(fmaxf(d2, 0.0f)) & 0xFFFFF800u) | (unsigned)j;
      unsigned nk0 = min(k[0], K);
      unsigned nk1 = med3u(K, k[0], k[1]);
      unsigned nk2 = med3u(K, k[1], k[2]);
      unsigned nk3 = med3u(K, k[2], k[3]);
      unsigned nk4 = med3u(K, k[3], k[4]);
      unsigned nk5 = med3u(K, k[4], k[5]);
      unsigned nk6 = med3u(K, k[5], k[6]);
      unsigned nk7 = med3u(K, k[6], k[7]);
      k[0] = nk0; k[1] = nk1; k[2] = nk2; k[3] = nk3;
      k[4] = nk4; k[5] = nk5; k[6] = nk6; k[7] = nk7;
    }
  }

  // ---- hierarchical cross-wave merge (u32, scratch overlaid on XH) ----
  if (wid >= 4) {
    int wl = (wid - 4) * 64 + lane;
#pragma unroll
    for (int s = 0; s < 8; ++s) MG[s * 256 + wl] = k[s];
  }
  __syncthreads();
  if (wid < 4) {
    unsigned p[8];
    int wl = wid * 64 + lane;
#pragma unroll
    for (int s = 0; s < 8; ++s) p[s] = MG[s * 256 + wl];
    merge8(k, p);
  }
  __syncthreads();
  if (wid == 2 || wid == 3) {
    int wl = (wid - 2) * 64 + lane;
#pragma unroll
    for (int s = 0; s < 8; ++s) MG[s * 128 + wl] = k[s];
  }
  __syncthreads();
  if (wid < 2) {
    unsigned p[8];
    int wl = wid * 64 + lane;
#pragma unroll
    for (int s = 0; s < 8; ++s) p[s] = MG[s * 128 + wl];
    merge8(k, p);
  }
  __syncthreads();
  if (wid == 1) {
#pragma unroll
    for (int s = 0; s < 8; ++s) MG[s * 64 + lane] = k[s];
  }
  __syncthreads();
  if (wid == 0) {
    unsigned p[8];
#pragma unroll
    for (int s = 0; s < 8; ++s) p[s] = MG[s * 64 + lane];
    merge8(k, p);

    // ---- exact re-rank of the 8 survivors (np-exact f32 d2, lex (d2bits,j))
    unsigned db[8], jj[8];
    const float4* __restrict__ pk = xyz2s + (size_t)b * 2048;
#pragma unroll
    for (int s = 0; s < 8; ++s) {
      unsigned j = k[s] & 2047u;
      float4 P = pk[j];
      float dot = __fadd_rn(__fadd_rn(__fmul_rn(qx, P.x), __fmul_rn(qy, P.y)),
                            __fmul_rn(qz, P.z));
      float d2 = __fsub_rn(__fadd_rn(s1, P.w), __fadd_rn(dot, dot));
      db[s] = __float_as_uint(fmaxf(d2, 0.0f));
      jj[s] = j;
    }
    // Batcher odd-even merge sort, 19 CEs, lexicographic (d2bits, j)
#define CEP(X, Y)                                                         \
  {                                                                       \
    bool s_ = (db[X] < db[Y]) || ((db[X] == db[Y]) && (jj[X] < jj[Y]));   \
    unsigned td_ = db[X], ti_ = jj[X];                                    \
    db[X] = s_ ? db[X] : db[Y]; jj[X] = s_ ? jj[X] : jj[Y];               \
    db[Y] = s_ ? db[Y] : td_;   jj[Y] = s_ ? jj[Y] : ti_;                 \
  }
    CEP(0, 1) CEP(2, 3) CEP(4, 5) CEP(6, 7)
    CEP(0, 2) CEP(1, 3) CEP(4, 6) CEP(5, 7)
    CEP(1, 2) CEP(5, 6)
    CEP(0, 4) CEP(1, 5) CEP(2, 6) CEP(3, 7)
    CEP(2, 4) CEP(3, 5)
    CEP(1, 2) CEP(3, 4) CEP(5, 6)
#undef CEP
    // sqrt + stable (d, idx) re-sort over top-4 (sqrt-collapse ties, np top_k)
    float e[4]; int ji[4];
#pragma unroll
    for (int s = 0; s < 4; ++s) {
      e[s] = __fsqrt_rn(__uint_as_float(db[s]));
      ji[s] = (int)jj[s];
    }
#define SW(X, Y)                                                          \
  {                                                                       \
    bool sw = (e[X] > e[Y]) || ((e[X] == e[Y]) && (ji[X] > ji[Y]));       \
    float td = e[X]; int ti = ji[X];                                      \
    e[X] = sw ? e[Y] : e[X]; ji[X] = sw ? ji[Y] : ji[X];                  \
    e[Y] = sw ? td : e[Y];   ji[Y] = sw ? ti : ji[Y];                     \
  }
    SW(0, 1) SW(1, 2) SW(2, 3) SW(0, 1) SW(1, 2) SW(0, 1)
#undef SW
    float c0 = fmaxf(e[0], 1e-8f), c1 = fmaxf(e[1], 1e-8f), c2 = fmaxf(e[2], 1e-8f);
    float u0 = 1.0f / c0, u1 = 1.0f / c1, u2 = 1.0f / c2;
    float ss = __fadd_rn(__fadd_rn(u0, u1), u2);
    W3s[lane * 3 + 0] = u0 / ss; W3s[lane * 3 + 1] = u1 / ss; W3s[lane * 3 + 2] = u2 / ss;
    ID3s[lane * 3 + 0] = ji[0]; ID3s[lane * 3 + 1] = ji[1]; ID3s[lane * 3 + 2] = ji[2];
  }
  __syncthreads();

  // ---- phase 3: interpolation -> X-tile in XH (bf16 [64][256], XOR-swizzled)
  {
    const int c = t & 255, half = t >> 8;
    const size_t f2b = (size_t)b * 2048 * 256;
#pragma unroll 2
    for (int qi = 0; qi < 32; ++qi) {
      int q = half * 32 + qi;
      int j0 = ID3s[q * 3 + 0], j1 = ID3s[q * 3 + 1], j2 = ID3s[q * 3 + 2];
      float W0 = W3s[q * 3 + 0], W1v = W3s[q * 3 + 1], W2v = W3s[q * 3 + 2];
      float v0 = __uint_as_float((unsigned)ft2[f2b + (size_t)j0 * 256 + c] << 16);
      float v1 = __uint_as_float((unsigned)ft2[f2b + (size_t)j1 * 256 + c] << 16);
      float v2 = __uint_as_float((unsigned)ft2[f2b + (size_t)j2 * 256 + c] << 16);
      float v = W0 * v0 + W1v * v1 + W2v * v2;
      int addr = (q * 512 + c * 2) ^ ((q & 7) << 4);
      *(unsigned short*)(XH + addr) = f2bf(v);
    }
  }
  __syncthreads();

  // ---- phase 4: GEMM1 (K=384 = 256 interp from LDS + 128 feats1 from global)
  f32x4 acc[2][4];
#pragma unroll
  for (int m = 0; m < 2; ++m)
#pragma unroll
    for (int n = 0; n < 4; ++n) acc[m][n] = (f32x4){0.f, 0.f, 0.f, 0.f};

#pragma unroll
  for (int kt = 0; kt < 8; ++kt) {
    bf16x8 a[2], bb[4];
#pragma unroll
    for (int m = 0; m < 2; ++m)
      a[m] = *(const bf16x8*)(wpk1 + ((size_t)(kt * 16 + wid * 2 + m) * 64 + lane) * 8);
#pragma unroll
    for (int nt = 0; nt < 4; ++nt) {
      int q = nt * 16 + l15;
      int addr = q * 512 + ((kt * 64 + l4 * 16) ^ ((q & 7) << 4));
      bb[nt] = *(const bf16x8*)(XH + addr);
    }
#pragma unroll
    for (int m = 0; m < 2; ++m)
#pragma unroll
      for (int nt = 0; nt < 4; ++nt)
        acc[m][nt] = __builtin_amdgcn_mfma_f32_16x16x32_bf16(a[m], bb[nt], acc[m][nt], 0, 0, 0);
  }
#pragma unroll
  for (int kt = 8; kt < 12; ++kt) {
    bf16x8 a[2], bb[4];
#pragma unroll
    for (int m = 0; m < 2; ++m)
      a[m] = *(const bf16x8*)(wpk1 + ((size_t)(kt * 16 + wid * 2 + m) * 64 + lane) * 8);
#pragma unroll
    for (int nt = 0; nt < 4; ++nt)
      bb[nt] = *(const bf16x8*)(ft1 + ((size_t)b * 8192 + n0 + nt * 16 + l15) * 128 +
                                (kt - 8) * 32 + l4 * 8);
#pragma unroll
    for (int m = 0; m < 2; ++m)
#pragma unroll
      for (int nt = 0; nt < 4; ++nt)
        acc[m][nt] = __builtin_amdgcn_mfma_f32_16x16x32_bf16(a[m], bb[nt], acc[m][nt], 0, 0, 0);
  }
  __syncthreads();   // all reads of XH (X) complete before H1 overwrites it

  // ---- epilogue 1: H1 = relu(bn(acc+b1)) -> XH bf16 swizzled ----
  const float BNINV = 0.99999500003749972f;   // 1/sqrt(1+1e-5)
#pragma unroll
  for (int m = 0; m < 2; ++m) {
    int cb = wid * 32 + m * 16 + l4 * 4;
    float gv[4], bv[4], ev[4];
#pragma unroll
    for (int r = 0; r < 4; ++r) {
      gv[r] = g1[cb + r] * BNINV; bv[r] = b1[cb + r]; ev[r] = be1[cb + r];
    }
#pragma unroll
    for (int nt = 0; nt < 4; ++nt) {
      int q = nt * 16 + l15;
      u16x4 pk4;
#pragma unroll
      for (int r = 0; r < 4; ++r)
        pk4[r] = f2bf(fmaxf((acc[m][nt][r] + bv[r]) * gv[r] + ev[r], 0.0f));
      *(u16x4*)(XH + ((q * 512 + cb * 2) ^ ((q & 7) << 4))) = pk4;
    }
  }
  __syncthreads();

  // ---- phase 5: GEMM2 (K=256 from XH) ----
#pragma unroll
  for (int m = 0; m < 2; ++m)
#pragma unroll
    for (int n = 0; n < 4; ++n) acc[m][n] = (f32x4){0.f, 0.f, 0.f, 0.f};
#pragma unroll
  for (int kt = 0; kt < 8; ++kt) {
    bf16x8 a[2], bb[4];
#pragma unroll
    for (int m = 0; m < 2; ++m)
      a[m] = *(const bf16x8*)(wpk2 + ((size_t)(kt * 16 + wid * 2 + m) * 64 + lane) * 8);
#pragma unroll
    for (int nt = 0; nt < 4; ++nt) {
      int q = nt * 16 + l15;
      int addr = q * 512 + ((kt * 64 + l4 * 16) ^ ((q & 7) << 4));
      bb[nt] = *(const bf16x8*)(XH + addr);
    }
#pragma unroll
    for (int m = 0; m < 2; ++m)
#pragma unroll
      for (int nt = 0; nt < 4; ++nt)
        acc[m][nt] = __builtin_amdgcn_mfma_f32_16x16x32_bf16(a[m], bb[nt], acc[m][nt], 0, 0, 0);
  }

  // ---- epilogue 2: out = relu(bn(acc+b2)) -> d_out f32 [b][o][n] ----
#pragma unroll
  for (int m = 0; m < 2; ++m) {
    int ob = wid * 32 + m * 16 + l4 * 4;
    float gv[4], bv[4], ev[4];
#pragma unroll
    for (int r = 0; r < 4; ++r) {
      gv[r] = g2[ob + r] * BNINV; bv[r] = b2[ob + r]; ev[r] = be2[ob + r];
    }
#pragma unroll
    for (int nt = 0; nt < 4; ++nt) {
      int nn = n0 + nt * 16 + l15;
#pragma unroll
      for (int r = 0; r < 4; ++r)
        out[((size_t)b * 256 + ob + r) * 8192 + nn] =
            fmaxf((acc[m][nt][r] + bv[r]) * gv[r] + ev[r], 0.0f);
    }
  }
}

extern "C" void kernel_launch(void* const* d_in, const int* in_sizes, int n_in,
                              void* d_out, int out_size, void* d_ws, size_t ws_size,
                              hipStream_t stream) {
  (void)in_sizes; (void)n_in; (void)out_size; (void)ws_size;
  const float* xyz1   = (const float*)d_in[0];
  const float* xyz2   = (const float*)d_in[1];
  const float* feats1 = (const float*)d_in[2];
  const float* feats2 = (const float*)d_in[3];
  const float* W1  = (const float*)d_in[4];
  const float* b1  = (const float*)d_in[5];
  const float* g1  = (const float*)d_in[6];
  const float* be1 = (const float*)d_in[7];
  const float* W2  = (const float*)d_in[8];
  const float* b2  = (const float*)d_in[9];
  const float* g2  = (const float*)d_in[10];
  const float* be2 = (const float*)d_in[11];
  float* out = (float*)d_out;

  // ws layout (25,755,648 B):
  //   [0,       196608)    wpk1 bf16
  //   [196608,  327680)    wpk2 bf16
  //   [327680,  589824)    xyz2s float4 [8][2048]
  //   [589824,  8978432)   ft2 bf16 [8][2048][256]
  //   [8978432, 25755648)  ft1 bf16 [8][8192][128]
  char* ws = (char*)d_ws;
  short*          wpk1  = (short*)(ws);
  short*          wpk2  = (short*)(ws + 196608);
  float4*         xyz2s = (float4*)(ws + 327680);
  unsigned short* ft2   = (unsigned short*)(ws + 589824);
  short*          ft1   = (short*)(ws + 8978432);

  prep<<<3776, 256, 0, stream>>>(feats1, feats2, xyz2, W1, W2,
                                 ft1, ft2, wpk1, wpk2, xyz2s);
  fused<<<1024, 512, 0, stream>>>(xyz1, xyz2s, ft2, ft1, wpk1, wpk2,
                                  b1, g1, be1, b2, g2, be2, out);
}